// Round 8
// baseline (1397.199 us; speedup 1.0000x reference)
//
#include <hip/hip_runtime.h>
#include <hip/hip_bf16.h>

#define BB 64
#define TT 64
#define FF 256
#define CC 64
#define GG 256   // 4*C
#define HP 264   // padded f-rows per batch: 4 zero + 256 + 4 zero
#define TFR 32   // f-rows per block
#define GST 260  // gbuf row stride (floats): 256 gate-cols + 4 pad

using frag_ab = __attribute__((ext_vector_type(8))) short;  // 8 bf16
using f32x4   = __attribute__((ext_vector_type(4))) float;

__device__ __forceinline__ float sigmoidf_(float x) {
    return 1.0f / (1.0f + __expf(-x));
}
__device__ __forceinline__ float tanhf_(float x) {
    const float e = __expf(2.0f * x);
    return 1.0f - 2.0f / (e + 1.0f);
}
__device__ __forceinline__ void split2(float v, short* hi, short* lo) {
    __hip_bfloat16 h = __float2bfloat16(v);
    __hip_bfloat16 l = __float2bfloat16(v - __bfloat162float(h));
    *hi = *reinterpret_cast<short*>(&h);
    *lo = *reinterpret_cast<short*>(&l);
}

// ---- prep: Wh -> packed [p=(k*2+kk)][g][cin32] hi/lo; Wx -> [g][32] hi/lo;
//      h0 -> padded (B,HP,C) hi/lo with zeroed halos in both ping-pong buffers
__global__ __launch_bounds__(256) void prep_kernel(
    const float* __restrict__ Wh, const float* __restrict__ Wx,
    const float* __restrict__ h0,
    short* __restrict__ WhPh, short* __restrict__ WhPl,
    short* __restrict__ WxTh, short* __restrict__ WxTl,
    short* __restrict__ hAh, short* __restrict__ hAl,
    short* __restrict__ hBh, short* __restrict__ hBl)
{
    const int n = blockIdx.x * 256 + threadIdx.x;
    if (n < BB * HP * CC) {
        const int c = n & 63;
        const int r = (n >> 6) % HP;
        const int b = n / (HP * CC);
        if (r < 4 || r >= 260) {
            hAh[n] = 0; hAl[n] = 0; hBh[n] = 0; hBl[n] = 0;
        } else {
            split2(h0[(b * FF + (r - 4)) * CC + c], &hAh[n], &hAl[n]);
        }
    }
    if (n < 9 * GG * CC) {
        const int c32 = n & 31;
        const int g = (n >> 5) & 255;
        const int p = n >> 13;
        const int k = p >> 1;
        const int cin = (p & 1) * 32 + c32;
        split2(Wh[(k * CC + cin) * GG + g], &WhPh[n], &WhPl[n]);
    }
    if (n < GG * 32) {
        const int kz = n & 31;
        const int g = n >> 5;
        split2(kz < 9 ? Wx[kz * GG + g] : 0.0f, &WxTh[n], &WxTl[n]);
    }
}

// ---- block = (b, 32-row f-tile), 4 waves; wave w owns g-cols [w*64, w*64+64)
__global__ __launch_bounds__(256, 2) void convlstm_step(
    const float* __restrict__ z,
    const short* __restrict__ hinh, const short* __restrict__ hinl,  // padded (B,HP,C)
    const float* __restrict__ c_in,
    const short* __restrict__ WhPh, const short* __restrict__ WhPl,
    const short* __restrict__ WxTh, const short* __restrict__ WxTl,
    const float* __restrict__ bias,
    short* __restrict__ houth, short* __restrict__ houtl,            // padded
    float* __restrict__ c_out,
    float* __restrict__ out, int t)
{
    __shared__ __align__(16) char hbyh[40 * 128];   // h hi tile rows f0-4..f0+35, swizzled
    __shared__ __align__(16) char hbyl[40 * 128];   // h lo tile
    __shared__ __align__(16) char zbyh[32 * 64];    // z hi tile [32 f][32 kz]
    __shared__ __align__(16) char zbyl[32 * 64];
    __shared__ __align__(16) float gbuf[TFR * GST]; // 32 f x 256 gate-cols (33.3 KB)

    const int b = blockIdx.x;
    const int f0 = blockIdx.y * TFR;
    const int tid = threadIdx.x;
    const int lane = tid & 63;
    const int w = tid >> 6;          // 0..3 : owns g-cols [w*64, w*64+64)

    const int rA = lane & 15;
    const int sA = lane >> 4;
    const int gbase = w * 64;
    const int bln = rA * 32 + sA * 8;

    // ---- early global loads: phase-0 B frags + epilogue c_in + bias
    frag_ab cbh[4], cbl[4];
    #pragma unroll
    for (int gtI = 0; gtI < 4; ++gtI) {
        const int o0 = (gbase + gtI * 16 + rA) * 32 + sA * 8;
        cbh[gtI] = *reinterpret_cast<const frag_ab*>(WhPh + o0);
        cbl[gtI] = *reinterpret_cast<const frag_ab*>(WhPl + o0);
    }
    const int flE = tid >> 3;             // epilogue row 0..31
    const int ch0E = (tid & 7) * 8;       // epilogue channel block
    const int cixE = (b * FF + f0 + flE) * CC + ch0E;
    const float4 cold0 = *reinterpret_cast<const float4*>(&c_in[cixE]);
    const float4 cold1 = *reinterpret_cast<const float4*>(&c_in[cixE + 4]);

    float bv[4];
    #pragma unroll
    for (int gtI = 0; gtI < 4; ++gtI) bv[gtI] = bias[gbase + gtI * 16 + rA];

    // ---- stage h tile rows f0..f0+39 (padded space; always in-bounds)
    for (int idx = tid; idx < 40 * 8; idx += 256) {
        const int row = idx >> 3, slot = idx & 7;
        const int off = (b * HP + f0 + row) * CC + slot * 8;
        const frag_ab vh = *reinterpret_cast<const frag_ab*>(hinh + off);
        const frag_ab vl = *reinterpret_cast<const frag_ab*>(hinl + off);
        const int a = row * 128 + ((slot ^ (row & 7)) << 4);
        *reinterpret_cast<frag_ab*>(&hbyh[a]) = vh;
        *reinterpret_cast<frag_ab*>(&hbyl[a]) = vl;
    }
    // ---- stage z tile [32 f][kz<9] hi+lo
    if (tid < 128) {
        const int row = tid >> 2, slot = tid & 3;
        const float* zr = z + ((long)b * TT + t) * FF;
        short vh[8], vl[8];
        #pragma unroll
        for (int j = 0; j < 8; ++j) {
            const int kz = slot * 8 + j;
            const int f = f0 + row - 4 + kz;
            const float val = (kz < 9 && f >= 0 && f < FF) ? zr[f] : 0.0f;
            split2(val, &vh[j], &vl[j]);
        }
        const int a = row * 64 + ((slot ^ (row & 3)) << 4);
        *reinterpret_cast<frag_ab*>(&zbyh[a]) = *reinterpret_cast<frag_ab*>(vh);
        *reinterpret_cast<frag_ab*>(&zbyl[a]) = *reinterpret_cast<frag_ab*>(vl);
    }
    __syncthreads();

    f32x4 acc[2][4];
    #pragma unroll
    for (int Mt = 0; Mt < 2; ++Mt)
        #pragma unroll
        for (int gtI = 0; gtI < 4; ++gtI)
            acc[Mt][gtI] = (f32x4){bv[gtI], bv[gtI], bv[gtI], bv[gtI]};

    // ---- 19 phases (18 Wh + 1 z-tap); B prefetched one phase ahead
    #pragma unroll
    for (int p = 0; p < 19; ++p) {
        frag_ab nbh[4], nbl[4];
        if (p < 17) {
            #pragma unroll
            for (int gtI = 0; gtI < 4; ++gtI) {
                const int o0 = ((p + 1) * GG + gbase + gtI * 16 + rA) * 32 + sA * 8;
                nbh[gtI] = *reinterpret_cast<const frag_ab*>(WhPh + o0);
                nbl[gtI] = *reinterpret_cast<const frag_ab*>(WhPl + o0);
            }
        } else if (p == 17) {
            #pragma unroll
            for (int gtI = 0; gtI < 4; ++gtI) {
                const int o0 = (gbase + gtI * 16 + rA) * 32 + sA * 8;
                nbh[gtI] = *reinterpret_cast<const frag_ab*>(WxTh + o0);
                nbl[gtI] = *reinterpret_cast<const frag_ab*>(WxTl + o0);
            }
        }
        // A fragments for this phase
        frag_ab ah[2], al[2];
        if (p < 18) {
            const int k = p >> 1, kk = p & 1;
            const int sl = kk * 4 + sA;
            #pragma unroll
            for (int Mt = 0; Mt < 2; ++Mt) {
                const int r = Mt * 16 + rA + k;
                const int a = r * 128 + ((sl ^ (r & 7)) << 4);
                ah[Mt] = *reinterpret_cast<const frag_ab*>(&hbyh[a]);
                al[Mt] = *reinterpret_cast<const frag_ab*>(&hbyl[a]);
            }
        } else {
            #pragma unroll
            for (int Mt = 0; Mt < 2; ++Mt) {
                const int r = Mt * 16 + rA;
                const int a = r * 64 + ((sA ^ (r & 3)) << 4);
                ah[Mt] = *reinterpret_cast<const frag_ab*>(&zbyh[a]);
                al[Mt] = *reinterpret_cast<const frag_ab*>(&zbyl[a]);
            }
        }
        __builtin_amdgcn_s_setprio(1);
        #pragma unroll
        for (int gtI = 0; gtI < 4; ++gtI) {
            #pragma unroll
            for (int Mt = 0; Mt < 2; ++Mt) {
                acc[Mt][gtI] = __builtin_amdgcn_mfma_f32_16x16x32_bf16(ah[Mt], cbh[gtI], acc[Mt][gtI], 0, 0, 0);
                acc[Mt][gtI] = __builtin_amdgcn_mfma_f32_16x16x32_bf16(ah[Mt], cbl[gtI], acc[Mt][gtI], 0, 0, 0);
                acc[Mt][gtI] = __builtin_amdgcn_mfma_f32_16x16x32_bf16(al[Mt], cbh[gtI], acc[Mt][gtI], 0, 0, 0);
            }
        }
        __builtin_amdgcn_s_setprio(0);
        if (p < 18) {
            #pragma unroll
            for (int gtI = 0; gtI < 4; ++gtI) { cbh[gtI] = nbh[gtI]; cbl[gtI] = nbl[gtI]; }
        }
    }

    // ---- scatter gates to LDS (full 32 rows x 256 cols, single pass)
    #pragma unroll
    for (int Mt = 0; Mt < 2; ++Mt)
        #pragma unroll
        for (int gtI = 0; gtI < 4; ++gtI) {
            float* gp = &gbuf[(Mt * 16 + sA * 4) * GST + gbase + gtI * 16 + rA];
            gp[0]       = acc[Mt][gtI][0];
            gp[GST]     = acc[Mt][gtI][1];
            gp[2 * GST] = acc[Mt][gtI][2];
            gp[3 * GST] = acc[Mt][gtI][3];
        }
    __syncthreads();

    // ---- LSTM cell update: thread -> (fl = tid>>3, 8 channels)
    const float* gr = &gbuf[flE * GST];
    const f32x4 gia = *reinterpret_cast<const f32x4*>(gr + ch0E);
    const f32x4 gib = *reinterpret_cast<const f32x4*>(gr + ch0E + 4);
    const f32x4 gja = *reinterpret_cast<const f32x4*>(gr + 64 + ch0E);
    const f32x4 gjb = *reinterpret_cast<const f32x4*>(gr + 64 + ch0E + 4);
    const f32x4 gfa = *reinterpret_cast<const f32x4*>(gr + 128 + ch0E);
    const f32x4 gfb = *reinterpret_cast<const f32x4*>(gr + 128 + ch0E + 4);
    const f32x4 goa = *reinterpret_cast<const f32x4*>(gr + 192 + ch0E);
    const f32x4 gob = *reinterpret_cast<const f32x4*>(gr + 192 + ch0E + 4);
    const float gi[8] = {gia[0], gia[1], gia[2], gia[3], gib[0], gib[1], gib[2], gib[3]};
    const float gj[8] = {gja[0], gja[1], gja[2], gja[3], gjb[0], gjb[1], gjb[2], gjb[3]};
    const float gf[8] = {gfa[0], gfa[1], gfa[2], gfa[3], gfb[0], gfb[1], gfb[2], gfb[3]};
    const float go[8] = {goa[0], goa[1], goa[2], goa[3], gob[0], gob[1], gob[2], gob[3]};
    const float co_[8] = {cold0.x, cold0.y, cold0.z, cold0.w, cold1.x, cold1.y, cold1.z, cold1.w};

    float hsum = 0.0f;
    float cv[8];
    short hh[8], hl[8];
    #pragma unroll
    for (int j = 0; j < 8; ++j) {
        const float cnew = co_[j] * sigmoidf_(gf[j] + 1.0f) + sigmoidf_(gi[j]) * tanhf_(gj[j]);
        const float hnew = tanhf_(cnew) * sigmoidf_(go[j]);
        cv[j] = cnew;
        split2(hnew, &hh[j], &hl[j]);
        hsum += hnew;
    }
    *reinterpret_cast<float4*>(&c_out[cixE])     = make_float4(cv[0], cv[1], cv[2], cv[3]);
    *reinterpret_cast<float4*>(&c_out[cixE + 4]) = make_float4(cv[4], cv[5], cv[6], cv[7]);
    const int hix = (b * HP + 4 + f0 + flE) * CC + ch0E;
    *reinterpret_cast<frag_ab*>(&houth[hix]) = *reinterpret_cast<frag_ab*>(hh);
    *reinterpret_cast<frag_ab*>(&houtl[hix]) = *reinterpret_cast<frag_ab*>(hl);

    // mean over 64 ch: 8 lanes (consecutive) each hold 8-ch partial
    hsum += __shfl_xor(hsum, 1);
    hsum += __shfl_xor(hsum, 2);
    hsum += __shfl_xor(hsum, 4);
    if ((tid & 7) == 0)
        out[(long)b * (TT * FF) + t * FF + f0 + flE] = tanhf_(hsum * (1.0f / 64.0f));
}

extern "C" void kernel_launch(void* const* d_in, const int* in_sizes, int n_in,
                              void* d_out, int out_size, void* d_ws, size_t ws_size,
                              hipStream_t stream) {
    const float* z    = (const float*)d_in[0];
    const float* h0   = (const float*)d_in[1];
    const float* c0   = (const float*)d_in[2];
    const float* Wx   = (const float*)d_in[3];
    const float* Wh   = (const float*)d_in[4];
    const float* bias = (const float*)d_in[5];
    float* out = (float*)d_out;

    const int SEp = BB * HP * CC;   // 1,081,344 (padded h elems)
    const int SE  = BB * FF * CC;   // 1,048,576
    short* hAh = (short*)d_ws;
    short* hAl = hAh + SEp;
    short* hBh = hAl + SEp;
    short* hBl = hBh + SEp;
    float* cW  = (float*)(hBl + SEp);
    short* WhPh = (short*)(cW + SE);
    short* WhPl = WhPh + 9 * GG * CC;
    short* WxTh = WhPl + 9 * GG * CC;
    short* WxTl = WxTh + GG * 32;

    prep_kernel<<<(SEp + 255) / 256, 256, 0, stream>>>(Wh, Wx, h0, WhPh, WhPl,
                                                       WxTh, WxTl, hAh, hAl, hBh, hBl);

    dim3 grid(BB, FF / TFR);  // 64 x 8 = 512 blocks -> 2 blocks/CU
    for (int t = 0; t < TT; ++t) {
        const short* hih = (t & 1) ? hBh : hAh;
        const short* hil = (t & 1) ? hBl : hAl;
        short* hoh = (t & 1) ? hAh : hBh;
        short* hol = (t & 1) ? hAl : hBl;
        const float* cin = (t == 0) ? c0 : cW;
        convlstm_step<<<grid, 256, 0, stream>>>(z, hih, hil, cin,
                                                WhPh, WhPl, WxTh, WxTl, bias,
                                                hoh, hol, cW, out, t);
    }
}

// Round 9
// 1065.658 us; speedup vs baseline: 1.3111x; 1.3111x over previous
//
#include <hip/hip_runtime.h>
#include <hip/hip_bf16.h>

#define BB 64
#define TT 64
#define FF 256
#define CC 64
#define GG 256   // 4*C
#define HP 264   // padded f-rows per batch: 4 zero + 256 + 4 zero
#define GSTE 68  // gbuf row stride (floats): 64 cols + 4 pad (16B-aligned rows)

using frag_ab = __attribute__((ext_vector_type(8))) short;  // 8 bf16
using f32x4   = __attribute__((ext_vector_type(4))) float;

__device__ __forceinline__ float sigmoidf_(float x) {
    return 1.0f / (1.0f + __expf(-x));
}
__device__ __forceinline__ float tanhf_(float x) {
    const float e = __expf(2.0f * x);
    return 1.0f - 2.0f / (e + 1.0f);
}
__device__ __forceinline__ void split2(float v, short* hi, short* lo) {
    __hip_bfloat16 h = __float2bfloat16(v);
    __hip_bfloat16 l = __float2bfloat16(v - __bfloat162float(h));
    *hi = *reinterpret_cast<short*>(&h);
    *lo = *reinterpret_cast<short*>(&l);
}
__device__ __forceinline__ float bf2f(short s) {
    return __uint_as_float(((unsigned)(unsigned short)s) << 16);
}

// ---- prep: Wh -> packed [p][g'][cin32] hi/lo with g' = ch*4+gate interleave;
//      Wx -> [g'][32] hi/lo; h0 -> padded (B,HP,C) hi/lo, zeroed halos
__global__ __launch_bounds__(256) void prep_kernel(
    const float* __restrict__ Wh, const float* __restrict__ Wx,
    const float* __restrict__ h0,
    short* __restrict__ WhPh, short* __restrict__ WhPl,
    short* __restrict__ WxTh, short* __restrict__ WxTl,
    short* __restrict__ hAh, short* __restrict__ hAl,
    short* __restrict__ hBh, short* __restrict__ hBl)
{
    const int n = blockIdx.x * 256 + threadIdx.x;
    if (n < BB * HP * CC) {
        const int c = n & 63;
        const int r = (n >> 6) % HP;
        const int b = n / (HP * CC);
        if (r < 4 || r >= 260) {
            hAh[n] = 0; hAl[n] = 0; hBh[n] = 0; hBl[n] = 0;
        } else {
            split2(h0[(b * FF + (r - 4)) * CC + c], &hAh[n], &hAl[n]);
        }
    }
    if (n < 9 * GG * CC) {
        const int c32 = n & 31;
        const int gp = (n >> 5) & 255;     // interleaved col: ch*4 + gate
        const int p = n >> 13;
        const int k = p >> 1;
        const int cin = (p & 1) * 32 + c32;
        const int g = (gp & 3) * 64 + (gp >> 2);   // original col
        split2(Wh[(k * CC + cin) * GG + g], &WhPh[n], &WhPl[n]);
    }
    if (n < GG * 32) {
        const int kz = n & 31;
        const int gp = n >> 5;
        const int g = (gp & 3) * 64 + (gp >> 2);
        split2(kz < 9 ? Wx[kz * GG + g] : 0.0f, &WxTh[n], &WxTl[n]);
    }
}

// ---- final out row (t = TT-1) from the final h state
__global__ __launch_bounds__(128) void finalize_out(
    const short* __restrict__ hh, const short* __restrict__ hl,
    float* __restrict__ out)
{
    const int b = blockIdx.x;
    const int f0 = blockIdx.y * 64;
    const int tid = threadIdx.x;
    const int fl = tid >> 1, part = tid & 1;
    const long hb = ((long)(b * HP + 4 + f0 + fl)) * CC + part * 32;
    float s = 0.0f;
    #pragma unroll
    for (int q = 0; q < 4; ++q) {
        const frag_ab vh = *reinterpret_cast<const frag_ab*>(hh + hb + q * 8);
        const frag_ab vl = *reinterpret_cast<const frag_ab*>(hl + hb + q * 8);
        #pragma unroll
        for (int j = 0; j < 8; ++j) s += bf2f(vh[j]) + bf2f(vl[j]);
    }
    s += __shfl_xor(s, 1);
    if (part == 0)
        out[(long)b * (TT * FF) + (TT - 1) * FF + f0 + fl] = tanhf_(s * (1.0f / 64.0f));
}

// ---- block = (b, 64-f-tile, 64-colgroup); 2 waves; wave owns 32 g'-cols
__global__ __launch_bounds__(128, 2) void convlstm_step(
    const float* __restrict__ z,
    const short* __restrict__ hinh, const short* __restrict__ hinl,  // padded (B,HP,C)
    const float* __restrict__ c_in,
    const short* __restrict__ WhPh, const short* __restrict__ WhPl,
    const short* __restrict__ WxTh, const short* __restrict__ WxTl,
    const float* __restrict__ bias,
    short* __restrict__ houth, short* __restrict__ houtl,            // padded
    float* __restrict__ c_out,
    float* __restrict__ out, int t)
{
    __shared__ __align__(16) char hbyh[72 * 128];   // h hi tile, swizzled (9.2 KB)
    __shared__ __align__(16) char hbyl[72 * 128];   // h lo tile
    __shared__ __align__(16) char zbyh[64 * 64];    // z hi tile [64 f][32 kz]
    __shared__ __align__(16) char zbyl[64 * 64];
    __shared__ __align__(16) float gbuf[32 * GSTE]; // 32 f x 64 g'-cols (8.7 KB)

    const int b = blockIdx.x;
    const int f0 = blockIdx.y * 64;
    const int cg = blockIdx.z;       // 0..3 : 64-col group = channels [cg*16, cg*16+16)
    const int tid = threadIdx.x;
    const int lane = tid & 63;
    const int w = tid >> 6;          // 0..1

    const int rA = lane & 15;
    const int sA = lane >> 4;
    const int gbase = cg * 64 + w * 32;   // global g'-col base of this wave

    // ---- early loads: phase-0 B frags, bias, epilogue c
    frag_ab cb[4];
    {
        const int o0 = (gbase + rA) * 32 + sA * 8;
        cb[0] = *reinterpret_cast<const frag_ab*>(WhPh + o0);
        cb[1] = *reinterpret_cast<const frag_ab*>(WhPh + o0 + 512);
        cb[2] = *reinterpret_cast<const frag_ab*>(WhPl + o0);
        cb[3] = *reinterpret_cast<const frag_ab*>(WhPl + o0 + 512);
    }
    float bv[2];
    #pragma unroll
    for (int gtI = 0; gtI < 2; ++gtI) {
        const int gq = gbase + gtI * 16 + rA;
        bv[gtI] = bias[((gq & 3) << 6) + (gq >> 2)];
    }
    const int flE = tid >> 2;             // epilogue row 0..31
    const int ch0E = cg * 16 + (tid & 3) * 4;   // global channel base (4 ch)
    const int cix0 = (b * FF + f0 + flE) * CC + ch0E;
    const int cix1 = cix0 + 32 * CC;
    const float4 cold0 = *reinterpret_cast<const float4*>(&c_in[cix0]);
    const float4 cold1 = *reinterpret_cast<const float4*>(&c_in[cix1]);

    // ---- stage h tile rows f0..f0+71 (padded space; always in-bounds)
    for (int idx = tid; idx < 72 * 8; idx += 128) {
        const int row = idx >> 3, slot = idx & 7;
        const int off = (b * HP + f0 + row) * CC + slot * 8;
        const frag_ab vh = *reinterpret_cast<const frag_ab*>(hinh + off);
        const frag_ab vl = *reinterpret_cast<const frag_ab*>(hinl + off);
        const int a = row * 128 + ((slot ^ (row & 7)) << 4);
        *reinterpret_cast<frag_ab*>(&hbyh[a]) = vh;
        *reinterpret_cast<frag_ab*>(&hbyl[a]) = vl;
    }
    // ---- stage z tile [64 f][kz<9] hi+lo
    for (int idx = tid; idx < 256; idx += 128) {
        const int row = idx >> 2, slot = idx & 3;
        const float* zr = z + ((long)b * TT + t) * FF;
        short vh[8], vl[8];
        #pragma unroll
        for (int j = 0; j < 8; ++j) {
            const int kz = slot * 8 + j;
            const int f = f0 + row - 4 + kz;
            const float val = (kz < 9 && f >= 0 && f < FF) ? zr[f] : 0.0f;
            split2(val, &vh[j], &vl[j]);
        }
        const int a = row * 64 + ((slot ^ (row & 3)) << 4);
        *reinterpret_cast<frag_ab*>(&zbyh[a]) = *reinterpret_cast<frag_ab*>(vh);
        *reinterpret_cast<frag_ab*>(&zbyl[a]) = *reinterpret_cast<frag_ab*>(vl);
    }
    // ---- deferred mean: out[t-1] from h_in (cg 0 only; kernel-boundary coherent)
    if (cg == 0 && t > 0) {
        const int fl = tid >> 1, part = tid & 1;
        const long hb = ((long)(b * HP + 4 + f0 + fl)) * CC + part * 32;
        float s = 0.0f;
        #pragma unroll
        for (int q = 0; q < 4; ++q) {
            const frag_ab vh = *reinterpret_cast<const frag_ab*>(hinh + hb + q * 8);
            const frag_ab vl = *reinterpret_cast<const frag_ab*>(hinl + hb + q * 8);
            #pragma unroll
            for (int j = 0; j < 8; ++j) s += bf2f(vh[j]) + bf2f(vl[j]);
        }
        s += __shfl_xor(s, 1);
        if (part == 0)
            out[(long)b * (TT * FF) + (t - 1) * FF + f0 + fl] = tanhf_(s * (1.0f / 64.0f));
    }
    __syncthreads();

    f32x4 acc[4][2];
    #pragma unroll
    for (int Mt = 0; Mt < 4; ++Mt) {
        acc[Mt][0] = (f32x4){bv[0], bv[0], bv[0], bv[0]};
        acc[Mt][1] = (f32x4){bv[1], bv[1], bv[1], bv[1]};
    }

    // ---- 19 phases (18 Wh + z-tap); B prefetched one phase ahead
    #pragma unroll
    for (int p = 0; p < 19; ++p) {
        frag_ab nb[4];
        if (p < 17) {
            const int o0 = ((p + 1) * GG + gbase + rA) * 32 + sA * 8;
            nb[0] = *reinterpret_cast<const frag_ab*>(WhPh + o0);
            nb[1] = *reinterpret_cast<const frag_ab*>(WhPh + o0 + 512);
            nb[2] = *reinterpret_cast<const frag_ab*>(WhPl + o0);
            nb[3] = *reinterpret_cast<const frag_ab*>(WhPl + o0 + 512);
        } else if (p == 17) {
            const int o0 = (gbase + rA) * 32 + sA * 8;
            nb[0] = *reinterpret_cast<const frag_ab*>(WxTh + o0);
            nb[1] = *reinterpret_cast<const frag_ab*>(WxTh + o0 + 512);
            nb[2] = *reinterpret_cast<const frag_ab*>(WxTl + o0);
            nb[3] = *reinterpret_cast<const frag_ab*>(WxTl + o0 + 512);
        }
        frag_ab ah[4], al[4];
        if (p < 18) {
            const int k = p >> 1, kk = p & 1;
            const int sl = kk * 4 + sA;
            #pragma unroll
            for (int Mt = 0; Mt < 4; ++Mt) {
                const int r = Mt * 16 + rA + k;
                const int a = r * 128 + ((sl ^ (r & 7)) << 4);
                ah[Mt] = *reinterpret_cast<const frag_ab*>(&hbyh[a]);
                al[Mt] = *reinterpret_cast<const frag_ab*>(&hbyl[a]);
            }
        } else {
            #pragma unroll
            for (int Mt = 0; Mt < 4; ++Mt) {
                const int r = Mt * 16 + rA;
                const int a = r * 64 + ((sA ^ (r & 3)) << 4);
                ah[Mt] = *reinterpret_cast<const frag_ab*>(&zbyh[a]);
                al[Mt] = *reinterpret_cast<const frag_ab*>(&zbyl[a]);
            }
        }
        __builtin_amdgcn_s_setprio(1);
        #pragma unroll
        for (int Mt = 0; Mt < 4; ++Mt) {
            acc[Mt][0] = __builtin_amdgcn_mfma_f32_16x16x32_bf16(ah[Mt], cb[0], acc[Mt][0], 0, 0, 0);
            acc[Mt][1] = __builtin_amdgcn_mfma_f32_16x16x32_bf16(ah[Mt], cb[1], acc[Mt][1], 0, 0, 0);
        }
        #pragma unroll
        for (int Mt = 0; Mt < 4; ++Mt) {
            acc[Mt][0] = __builtin_amdgcn_mfma_f32_16x16x32_bf16(ah[Mt], cb[2], acc[Mt][0], 0, 0, 0);
            acc[Mt][1] = __builtin_amdgcn_mfma_f32_16x16x32_bf16(ah[Mt], cb[3], acc[Mt][1], 0, 0, 0);
        }
        #pragma unroll
        for (int Mt = 0; Mt < 4; ++Mt) {
            acc[Mt][0] = __builtin_amdgcn_mfma_f32_16x16x32_bf16(al[Mt], cb[0], acc[Mt][0], 0, 0, 0);
            acc[Mt][1] = __builtin_amdgcn_mfma_f32_16x16x32_bf16(al[Mt], cb[1], acc[Mt][1], 0, 0, 0);
        }
        __builtin_amdgcn_s_setprio(0);
        if (p < 18) { cb[0] = nb[0]; cb[1] = nb[1]; cb[2] = nb[2]; cb[3] = nb[3]; }
    }

    // ---- two-pass epilogue through 32-row gbuf (local cols, interleaved gates)
    #pragma unroll
    for (int pass = 0; pass < 2; ++pass) {
        if (pass) __syncthreads();
        #pragma unroll
        for (int Mh = 0; Mh < 2; ++Mh) {
            const int Mt = pass * 2 + Mh;
            #pragma unroll
            for (int gtI = 0; gtI < 2; ++gtI) {
                float* gp = &gbuf[(Mh * 16 + sA * 4) * GSTE + w * 32 + gtI * 16 + rA];
                gp[0]        = acc[Mt][gtI][0];
                gp[GSTE]     = acc[Mt][gtI][1];
                gp[2 * GSTE] = acc[Mt][gtI][2];
                gp[3 * GSTE] = acc[Mt][gtI][3];
            }
        }
        __syncthreads();

        const int f = f0 + pass * 32 + flE;
        const float* gr = &gbuf[flE * GSTE + (tid & 3) * 16];
        const f32x4 v0 = *reinterpret_cast<const f32x4*>(gr);
        const f32x4 v1 = *reinterpret_cast<const f32x4*>(gr + 4);
        const f32x4 v2 = *reinterpret_cast<const f32x4*>(gr + 8);
        const f32x4 v3 = *reinterpret_cast<const f32x4*>(gr + 12);
        const float4 cold = pass ? cold1 : cold0;
        const float co_[4] = {cold.x, cold.y, cold.z, cold.w};

        float cv[4];
        short hh[4], hl[4];
        #pragma unroll
        for (int j = 0; j < 4; ++j) {
            const f32x4 g = (j == 0) ? v0 : (j == 1) ? v1 : (j == 2) ? v2 : v3;
            const float cnew = co_[j] * sigmoidf_(g[2] + 1.0f) + sigmoidf_(g[0]) * tanhf_(g[1]);
            const float hnew = tanhf_(cnew) * sigmoidf_(g[3]);
            cv[j] = cnew;
            split2(hnew, &hh[j], &hl[j]);
        }
        const int cix = (b * FF + f) * CC + ch0E;
        *reinterpret_cast<float4*>(&c_out[cix]) = make_float4(cv[0], cv[1], cv[2], cv[3]);
        const int hix = (b * HP + 4 + f) * CC + ch0E;
        *reinterpret_cast<uint2*>(&houth[hix]) = *reinterpret_cast<uint2*>(hh);
        *reinterpret_cast<uint2*>(&houtl[hix]) = *reinterpret_cast<uint2*>(hl);
    }
}

extern "C" void kernel_launch(void* const* d_in, const int* in_sizes, int n_in,
                              void* d_out, int out_size, void* d_ws, size_t ws_size,
                              hipStream_t stream) {
    const float* z    = (const float*)d_in[0];
    const float* h0   = (const float*)d_in[1];
    const float* c0   = (const float*)d_in[2];
    const float* Wx   = (const float*)d_in[3];
    const float* Wh   = (const float*)d_in[4];
    const float* bias = (const float*)d_in[5];
    float* out = (float*)d_out;

    const int SEp = BB * HP * CC;   // 1,081,344 (padded h elems)
    const int SE  = BB * FF * CC;   // 1,048,576
    short* hAh = (short*)d_ws;
    short* hAl = hAh + SEp;
    short* hBh = hAl + SEp;
    short* hBl = hBh + SEp;
    float* cW  = (float*)(hBl + SEp);
    short* WhPh = (short*)(cW + SE);
    short* WhPl = WhPh + 9 * GG * CC;
    short* WxTh = WhPl + 9 * GG * CC;
    short* WxTl = WxTh + GG * 32;

    prep_kernel<<<(SEp + 255) / 256, 256, 0, stream>>>(Wh, Wx, h0, WhPh, WhPl,
                                                       WxTh, WxTl, hAh, hAl, hBh, hBl);

    dim3 grid(BB, FF / 64, 4);  // 64 x 4 x 4 = 1024 blocks -> 4 blocks/CU
    for (int t = 0; t < TT; ++t) {
        const short* hih = (t & 1) ? hBh : hAh;
        const short* hil = (t & 1) ? hBl : hAl;
        short* hoh = (t & 1) ? hAh : hBh;
        short* hol = (t & 1) ? hAl : hBl;
        const float* cin = (t == 0) ? c0 : cW;
        convlstm_step<<<grid, 128, 0, stream>>>(z, hih, hil, cin,
                                                WhPh, WhPl, WxTh, WxTl, bias,
                                                hoh, hol, cW, out, t);
    }
    // out[TT-1] from final h (in hA after odd last step)
    finalize_out<<<dim3(BB, FF / 64), 128, 0, stream>>>(hAh, hAl, out);
}